// Round 4
// baseline (282.556 us; speedup 1.0000x reference)
//
#include <hip/hip_runtime.h>
#include <cstdint>
#include <math.h>

// MHA: B=2, S=2048, D_MODEL=1024, H=16, D_HEAD=64.
// merged cvt(fp32->bf16, W transposed) -> fused QKV GEMM (bf16 MFMA, 128x64
// tiles, 1536 blocks = 6/CU for latency hiding via block TLP) -> flash
// attention (32x32x16 MFMA, S^T layout, no-max exp2 softmax) -> final GEMM
// (64x64 tiles, 1024 blocks = 4/CU, fp32 out).

typedef __bf16 bf16;
typedef __bf16 bf16x2 __attribute__((ext_vector_type(2)));
typedef __bf16 bf16x4 __attribute__((ext_vector_type(4)));
typedef __bf16 bf16x8 __attribute__((ext_vector_type(8)));
typedef float f32x4 __attribute__((ext_vector_type(4)));
typedef float f32x16 __attribute__((ext_vector_type(16)));
typedef unsigned u32x4 __attribute__((ext_vector_type(4)));

__device__ __forceinline__ void gl2lds16(const void* g, void* l) {
  __builtin_amdgcn_global_load_lds(
      (const __attribute__((address_space(1))) unsigned int*)g,
      (__attribute__((address_space(3))) unsigned int*)l,
      16, 0, 0);
}

__device__ __forceinline__ unsigned pkbf(float a, float b) {
  bf16x2 t;
  t[0] = (bf16)a;
  t[1] = (bf16)b;
  return __builtin_bit_cast(unsigned, t);
}

// ---------------- merged conversions (one dispatch) ----------------
// blocks [0,12288): q/k/v fp32->bf16 (4 elems/thread)
// blocks [12288,24576): Wq/Wk/Wv [16][1024][64] -> WT [n=h*64+e][d]
// blocks [24576,28672): Wo [1024][1024] -> WoT [n][k]
__global__ __launch_bounds__(256) void k_cvt_all(const float* __restrict__ q,
                                                 const float* __restrict__ k,
                                                 const float* __restrict__ v,
                                                 const float* __restrict__ Wq,
                                                 const float* __restrict__ Wk,
                                                 const float* __restrict__ Wv,
                                                 const float* __restrict__ Wo,
                                                 bf16* __restrict__ qkv,
                                                 bf16* __restrict__ WT,
                                                 bf16* __restrict__ WoT) {
  const int bid = blockIdx.x;
  if (bid < 12288) {
    const int by = bid >> 12, bx = bid & 4095;
    const float* in = by == 0 ? q : (by == 1 ? k : v);
    bf16* out = qkv + (size_t)by * 4194304;
    const size_t i = ((size_t)bx * 256 + threadIdx.x) * 4;
    const float4 vv = *(const float4*)(in + i);
    bf16x4 o;
    o[0] = (bf16)vv.x; o[1] = (bf16)vv.y; o[2] = (bf16)vv.z; o[3] = (bf16)vv.w;
    *(bf16x4*)(out + i) = o;
  } else if (bid < 24576) {
    const int b2 = bid - 12288;
    const int by = b2 >> 12;
    const float* W = by == 0 ? Wq : (by == 1 ? Wk : Wv);
    bf16* out = WT + (size_t)by * 1048576;
    const int idx = (b2 & 4095) * 256 + threadIdx.x;  // 1M
    const int n = idx >> 10, d = idx & 1023;
    out[idx] = (bf16)W[((n >> 6) << 16) + (d << 6) + (n & 63)];
  } else {
    const int idx = (bid - 24576) * 256 + threadIdx.x;  // 1M
    const int n = idx >> 10, kk = idx & 1023;
    WoT[idx] = (bf16)Wo[(kk << 10) + n];
  }
}

// ---------------- fused QKV GEMM: M=4096, K=1024, N=3072, 128x64 tiles ----------------
// 1536 blocks (6/CU): latency hiding via block-level TLP. Per-output math is
// bit-identical to the 128x128 version (same fragment k-slot order, same k0
// accumulation sequence).
__global__ __launch_bounds__(256) void k_gemm_qkv(const bf16* __restrict__ Abase,
                                                  const bf16* __restrict__ Bt,
                                                  const float* __restrict__ bq,
                                                  const float* __restrict__ bk,
                                                  const float* __restrict__ bv,
                                                  bf16* __restrict__ Qh,
                                                  bf16* __restrict__ Kh,
                                                  bf16* __restrict__ Vt) {
  __shared__ __align__(16) bf16 Alds[4096];  // 128 rows x 32 k
  __shared__ __align__(16) bf16 Blds[2048];  // 64 rows x 32 k
  const int t = threadIdx.x;
  const int w = t >> 6;
  const int lane = t & 63;
  const int lane15 = lane & 15;
  const int quad = lane >> 4;
  const int wm = w >> 1, wn = w & 1;
  const int mb = blockIdx.x, nb = blockIdx.y;  // nb in [0,48)
  const int sel = nb >> 4;  // 0=Q,1=K,2=V (uniform per block)
  const int nb2 = nb & 15;

  const bf16* A = Abase + (size_t)sel * 4194304;
  const int ms = t & 127;
  const int c0 = t >> 7;
  const bf16* Ag = A + (size_t)(mb * 128 + ms) * 1024 + c0 * 8;
  const bf16* Bg = Bt + (size_t)(nb * 64 + (t & 63)) * 1024 + (t >> 6) * 8;
  bf16* Al0 = Alds + w * 512;
  bf16* Al1 = Alds + 2048 + w * 512;
  bf16* Bl = Blds + w * 512;  // layout [kchunk=w][row 0..63][8]

  f32x4 acc[4][2] = {};

  for (int k0 = 0; k0 < 1024; k0 += 32) {
    __syncthreads();
    gl2lds16(Ag + k0, Al0);
    gl2lds16(Ag + k0 + 16, Al1);
    gl2lds16(Bg + k0, Bl);
    __syncthreads();
    bf16x8 af[4], bfr[2];
#pragma unroll
    for (int i = 0; i < 4; ++i)
      af[i] = *(const bf16x8*)(Alds + (quad * 128 + wm * 64 + i * 16 + lane15) * 8);
#pragma unroll
    for (int j = 0; j < 2; ++j)
      bfr[j] = *(const bf16x8*)(Blds + (quad * 64 + wn * 32 + j * 16 + lane15) * 8);
#pragma unroll
    for (int i = 0; i < 4; ++i)
#pragma unroll
      for (int j = 0; j < 2; ++j)
        acc[i][j] = __builtin_amdgcn_mfma_f32_16x16x32_bf16(af[i], bfr[j], acc[i][j], 0, 0, 0);
  }

  // scale Q by 0.125*log2(e) so attention can use exp2 directly
  const float scale = sel == 0 ? 0.18033688011112042f : 1.0f;
  const float* bias = sel == 0 ? bq : (sel == 1 ? bk : bv);
  const int mbase = mb * 128 + wm * 64;
  const int nbase = nb2 * 64 + wn * 32;
  if (sel < 2) {
    bf16* outp = sel == 0 ? Qh : Kh;
#pragma unroll
    for (int j = 0; j < 2; ++j) {
      const int n = nbase + j * 16 + lane15;  // 0..1023
      const float bvl = bias[n];
      const int h = n >> 6, e = n & 63;
#pragma unroll
      for (int i = 0; i < 4; ++i) {
#pragma unroll
        for (int r = 0; r < 4; ++r) {
          const int m = mbase + i * 16 + quad * 4 + r;
          const float vv = (acc[i][j][r] + bvl) * scale;
          const int b = m >> 11, s = m & 2047;
          outp[(size_t)(b * 16 + h) * 131072 + s * 64 + e] = (bf16)vv;
        }
      }
    }
  } else {
    // V transposed [b,h,e,s]: r -> s contiguous, pack bf16x4 (8B) stores
#pragma unroll
    for (int j = 0; j < 2; ++j) {
      const int n = nbase + j * 16 + lane15;
      const float bvl = bias[n];
      const int h = n >> 6, e = n & 63;
#pragma unroll
      for (int i = 0; i < 4; ++i) {
        const int m = mbase + i * 16 + quad * 4;
        const int b = m >> 11, s = m & 2047;
        bf16x4 o;
#pragma unroll
        for (int r = 0; r < 4; ++r) o[r] = (bf16)(acc[i][j][r] + bvl);
        *(bf16x4*)(Vt + (size_t)(b * 16 + h) * 131072 + e * 2048 + s) = o;
      }
    }
  }
}

// ---------------- flash attention ----------------
// Qh/Kh: [bh][2048][64] (Q pre-scaled, log2-domain); Vt: [bh][64][2048].
// 512-thr blocks (8 waves): waves 0-3 keys [0,1024), waves 4-7 keys [1024,2048),
// wave handles 32 q-rows (q-group = w&3). 64-key tiles, 32x32x16 MFMA, S^T
// layout, no-max exp2 softmax, dbuf prefetch, in-block merge via LDS.
__global__ __launch_bounds__(512, 4) void k_attn(const bf16* __restrict__ Qh,
                                                 const bf16* __restrict__ Kh,
                                                 const bf16* __restrict__ Vt,
                                                 bf16* __restrict__ attn) {
  __shared__ __align__(16) bf16 lds[32768];  // 64 KiB: per half 16K elems (K dbuf 0/4096, V 8192/12288)
  const int t = threadIdx.x;
  const int w = t >> 6;        // 0..7
  const int lane = t & 63;
  const int lane31 = lane & 31;
  const int hi = lane >> 5;
  const int bh = blockIdx.y;
  const bf16* Qp = Qh + (size_t)bh * 131072;
  const bf16* Kp = Kh + (size_t)bh * 131072;
  const bf16* Vp = Vt + (size_t)bh * 131072;
  const int h = w >> 2;        // key-half
  const int q0 = blockIdx.x * 128 + (w & 3) * 32;

  // Q B-frags (n=q=lane31, k = kc*16 + hi*8 + j), loaded once
  bf16x8 aq[4];
#pragma unroll
  for (int kc = 0; kc < 4; ++kc)
    aq[kc] = *(const bf16x8*)(Qp + (size_t)(q0 + lane31) * 64 + kc * 16 + hi * 8);

  // swizzled LDS frag addresses (elements): row=lane31, chunk c = cc*2+hi
  int raddr[4];
#pragma unroll
  for (int cc = 0; cc < 4; ++cc)
    raddr[cc] = lane31 * 64 + (((cc * 2 + hi + lane31) & 7) << 3);

  // staging (per wave: 2 K-chunks + 2 V-chunks of 64 lanes x 16B, both halves)
  const bf16* kg[2];
  const bf16* vg[2];
  int kdst[2], vdst[2];
#pragma unroll
  for (int i = 0; i < 2; ++i) {
    const int cid = w * 2 + i;                   // 0..15
    const int half = cid >> 3;
    const int sl = ((cid & 7) << 6) + lane;      // 0..511 within half
    const int row = sl >> 3;
    const int c = ((sl & 7) - row) & 7;
    kg[i] = Kp + ((size_t)(half << 10) + row) * 64 + c * 8;
    vg[i] = Vp + (size_t)row * 2048 + (half << 10) + c * 8;
    kdst[i] = (half << 14) + ((cid & 7) << 9);
    vdst[i] = kdst[i] + 8192;
  }

  f32x16 O[2] = {};
  float l_ = 0.f;

  // prologue: stage tile 0 into buffer 0
#pragma unroll
  for (int i = 0; i < 2; ++i) {
    gl2lds16(kg[i], lds + kdst[i]);
    gl2lds16(vg[i], lds + vdst[i]);
  }

#pragma unroll 2
  for (int it = 0; it < 16; ++it) {
    const int bufo = (it & 1) << 12;
    __syncthreads();  // buffer[it&1] ready
    if (it + 1 < 16) {
      const int po = bufo ^ 4096;
#pragma unroll
      for (int i = 0; i < 2; ++i) {
        gl2lds16(kg[i] + (size_t)(it + 1) * 4096, lds + kdst[i] + po);
        gl2lds16(vg[i] + (it + 1) * 64, lds + vdst[i] + po);
      }
    }

    // ---- S^T = K * Q^T (rows=keys, cols=q) ----
    const bf16* Kl = lds + (h << 14) + bufo;
    f32x16 sa = {}, sb = {};
#pragma unroll
    for (int kc = 0; kc < 4; ++kc) {
      bf16x8 a0 = *(const bf16x8*)(Kl + raddr[kc]);
      bf16x8 a1 = *(const bf16x8*)(Kl + 2048 + raddr[kc]);
      sa = __builtin_amdgcn_mfma_f32_32x32x16_bf16(a0, aq[kc], sa, 0, 0, 0);
      sb = __builtin_amdgcn_mfma_f32_32x32x16_bf16(a1, aq[kc], sb, 0, 0, 0);
    }

    // ---- no-max exp2 softmax (scores bounded; P and l unnormalized) ----
    float rs = 0.f;
#pragma unroll
    for (int r = 0; r < 16; ++r) {
      sa[r] = __builtin_amdgcn_exp2f(sa[r]);
      sb[r] = __builtin_amdgcn_exp2f(sb[r]);
      rs += sa[r] + sb[r];
    }
    rs += __shfl_xor(rs, 32);
    l_ += rs;

    // ---- pack P pairs (C-reg pairs = consecutive keys) ----
    unsigned P2[2][8];
#pragma unroll
    for (int kq = 0; kq < 8; ++kq) {
      P2[0][kq] = pkbf(sa[2 * kq], sa[2 * kq + 1]);
      P2[1][kq] = pkbf(sb[2 * kq], sb[2 * kq + 1]);
    }

    // ---- transform C-layout -> B-frag (lane-half exchange) + PV ----
    const bf16* Vl = lds + (h << 14) + 8192 + bufo;
#pragma unroll
    for (int kk = 0; kk < 4; ++kk) {
      const int kmt = kk >> 1, kc = kk & 1;
      const unsigned mineA = hi ? P2[kmt][4 * kc + 2] : P2[kmt][4 * kc];
      const unsigned mineB = hi ? P2[kmt][4 * kc + 3] : P2[kmt][4 * kc + 1];
      const unsigned sendA = hi ? P2[kmt][4 * kc] : P2[kmt][4 * kc + 2];
      const unsigned sendB = hi ? P2[kmt][4 * kc + 1] : P2[kmt][4 * kc + 3];
      const unsigned ZA = (unsigned)__shfl_xor((int)sendA, 32);
      const unsigned ZB = (unsigned)__shfl_xor((int)sendB, 32);
      u32x4 bpi;
      bpi[0] = hi ? ZA : mineA;
      bpi[1] = hi ? ZB : mineB;
      bpi[2] = hi ? mineA : ZA;
      bpi[3] = hi ? mineB : ZB;
      const bf16x8 bp = __builtin_bit_cast(bf16x8, bpi);
#pragma unroll
      for (int emt = 0; emt < 2; ++emt) {
        bf16x8 av = *(const bf16x8*)(Vl + emt * 2048 + raddr[kk]);
        O[emt] = __builtin_amdgcn_mfma_f32_32x32x16_bf16(av, bp, O[emt], 0, 0, 0);
      }
    }
  }

  // ---- in-block merge of the two key-halves ----
  float* fl = (float*)lds;
  __syncthreads();
  if (w >= 4) {
    // raw register dump; lower wave reads with identical indexing
#pragma unroll
    for (int emt = 0; emt < 2; ++emt)
#pragma unroll
      for (int r = 0; r < 16; ++r)
        fl[(w - 4) * 2048 + (emt * 16 + r) * 64 + lane] = O[emt][r];
    if (lane < 32) fl[8192 + (w - 4) * 32 + lane] = l_;
  }
  __syncthreads();
  if (w < 4) {
#pragma unroll
    for (int emt = 0; emt < 2; ++emt)
#pragma unroll
      for (int r = 0; r < 16; ++r)
        O[emt][r] += fl[w * 2048 + (emt * 16 + r) * 64 + lane];
    const float lsum = l_ + fl[8192 + w * 32 + lane31];
    const float inv = 1.0f / lsum;

    // epilogue: O^T[e][q] -> attn[b][q][h*64+e]
    const int b = bh >> 4, hh = bh & 15;
    const int q = q0 + lane31;
    bf16* orow = attn + (size_t)(b * 2048 + q) * 1024 + hh * 64;
#pragma unroll
    for (int emt = 0; emt < 2; ++emt) {
#pragma unroll
      for (int kp = 0; kp < 8; ++kp) {
        const int r = 2 * kp;
        const int e0 = emt * 32 + (r & 3) + 8 * (kp >> 1) + 4 * hi;
        bf16x2 pr;
        pr[0] = (bf16)(O[emt][r] * inv);
        pr[1] = (bf16)(O[emt][r + 1] * inv);
        *(bf16x2*)(orow + e0) = pr;
      }
    }
  }
}

// ---------------- final GEMM: 64x64 tile, M=4096 K=1024 N=1024, fp32 out ----------------
// 1024 blocks (4/CU). 2x2 waves of 32x32; per-output math bit-identical to the
// previous 128x64 version (same fragment k-order, same accumulation sequence).
__global__ __launch_bounds__(256) void k_gemm2(const bf16* __restrict__ A,
                                               const bf16* __restrict__ Bt,
                                               const float* __restrict__ bias,
                                               float* __restrict__ outp) {
  __shared__ __align__(16) bf16 Alds[2048];  // 64 rows x 32 k
  __shared__ __align__(16) bf16 Blds[2048];
  const int t = threadIdx.x;
  const int w = t >> 6;
  const int lane = t & 63;
  const int lane15 = lane & 15;
  const int quad = lane >> 4;
  const int wm = w >> 1, wn = w & 1;
  const int mb = blockIdx.x, nb = blockIdx.y;  // 64 x 16

  const bf16* Ag = A + (size_t)(mb * 64 + (t & 63)) * 1024 + (t >> 6) * 8;
  const bf16* Bg = Bt + (size_t)(nb * 64 + (t & 63)) * 1024 + (t >> 6) * 8;
  bf16* Al = Alds + w * 512;  // [kchunk=w][row 0..63][8]
  bf16* Bl = Blds + w * 512;

  f32x4 acc[2][2] = {};

  for (int k0 = 0; k0 < 1024; k0 += 32) {
    __syncthreads();
    gl2lds16(Ag + k0, Al);
    gl2lds16(Bg + k0, Bl);
    __syncthreads();
    bf16x8 af[2], bfr[2];
#pragma unroll
    for (int i = 0; i < 2; ++i)
      af[i] = *(const bf16x8*)(Alds + (quad * 64 + wm * 32 + i * 16 + lane15) * 8);
#pragma unroll
    for (int j = 0; j < 2; ++j)
      bfr[j] = *(const bf16x8*)(Blds + (quad * 64 + wn * 32 + j * 16 + lane15) * 8);
#pragma unroll
    for (int i = 0; i < 2; ++i)
#pragma unroll
      for (int j = 0; j < 2; ++j)
        acc[i][j] = __builtin_amdgcn_mfma_f32_16x16x32_bf16(af[i], bfr[j], acc[i][j], 0, 0, 0);
  }

  const int mbase = mb * 64 + wm * 32;
  const int nbase = nb * 64 + wn * 32;
#pragma unroll
  for (int j = 0; j < 2; ++j) {
    const int n = nbase + j * 16 + lane15;
    const float bv = bias[n];
#pragma unroll
    for (int i = 0; i < 2; ++i) {
#pragma unroll
      for (int r = 0; r < 4; ++r) {
        const int m = mbase + i * 16 + quad * 4 + r;
        outp[(size_t)m * 1024 + n] = acc[i][j][r] + bv;
      }
    }
  }
}

// ---------------- launch ----------------
extern "C" void kernel_launch(void* const* d_in, const int* in_sizes, int n_in,
                              void* d_out, int out_size, void* d_ws, size_t ws_size,
                              hipStream_t stream) {
  (void)in_sizes; (void)n_in; (void)out_size; (void)ws_size;
  const float* q = (const float*)d_in[0];
  const float* k = (const float*)d_in[1];
  const float* v = (const float*)d_in[2];
  const float* Wq = (const float*)d_in[3];
  const float* bq = (const float*)d_in[4];
  const float* Wk = (const float*)d_in[5];
  const float* bk = (const float*)d_in[6];
  const float* Wv = (const float*)d_in[7];
  const float* bv = (const float*)d_in[8];
  const float* Wo = (const float*)d_in[9];
  const float* bo = (const float*)d_in[10];

  bf16* ws = (bf16*)d_ws;
  bf16* qkv = ws;                   // qb/kb/vb: 3 x 4M elems
  bf16* WqkvT = qkv + 12582912;     // 3 x 1M
  bf16* WoT = WqkvT + 3145728;      // 1M
  bf16* Qh = WoT + 1048576;         // 4M
  bf16* Kh = Qh + 4194304;          // 4M
  bf16* Vt = Kh + 4194304;          // 4M
  bf16* attnb = Vt + 4194304;       // 4M  (total 32M elems = 64 MiB)

  k_cvt_all<<<28672, 256, 0, stream>>>(q, k, v, Wq, Wk, Wv, Wo, qkv, WqkvT, WoT);
  k_gemm_qkv<<<dim3(32, 48), 256, 0, stream>>>(qkv, WqkvT, bq, bk, bv, Qh, Kh, Vt);
  k_attn<<<dim3(16, 32), 512, 0, stream>>>(Qh, Kh, Vt, attnb);
  k_gemm2<<<dim3(64, 16), 256, 0, stream>>>(attnb, WoT, bo, (float*)d_out);
}

// Round 5
// 261.703 us; speedup vs baseline: 1.0797x; 1.0797x over previous
//
#include <hip/hip_runtime.h>
#include <cstdint>
#include <math.h>

// MHA: B=2, S=2048, D_MODEL=1024, H=16, D_HEAD=64.
// merged cvt(fp32->bf16, W transposed) -> fused QKV GEMM (256x256 tile, BK=64,
// 8 waves, counted-vmcnt pipeline, XOR-swizzled LDS, XCD-swizzled grid) ->
// flash attention (32x32x16 MFMA, S^T layout, no-max exp2 softmax) -> final
// GEMM (64x64 tiles, fp32 out).

typedef __bf16 bf16;
typedef __bf16 bf16x2 __attribute__((ext_vector_type(2)));
typedef __bf16 bf16x4 __attribute__((ext_vector_type(4)));
typedef __bf16 bf16x8 __attribute__((ext_vector_type(8)));
typedef float f32x4 __attribute__((ext_vector_type(4)));
typedef float f32x16 __attribute__((ext_vector_type(16)));
typedef unsigned u32x4 __attribute__((ext_vector_type(4)));

__device__ __forceinline__ void gl2lds16(const void* g, void* l) {
  __builtin_amdgcn_global_load_lds(
      (const __attribute__((address_space(1))) unsigned int*)g,
      (__attribute__((address_space(3))) unsigned int*)l,
      16, 0, 0);
}

__device__ __forceinline__ unsigned pkbf(float a, float b) {
  bf16x2 t;
  t[0] = (bf16)a;
  t[1] = (bf16)b;
  return __builtin_bit_cast(unsigned, t);
}

// ---------------- merged conversions (one dispatch) ----------------
__global__ __launch_bounds__(256) void k_cvt_all(const float* __restrict__ q,
                                                 const float* __restrict__ k,
                                                 const float* __restrict__ v,
                                                 const float* __restrict__ Wq,
                                                 const float* __restrict__ Wk,
                                                 const float* __restrict__ Wv,
                                                 const float* __restrict__ Wo,
                                                 bf16* __restrict__ qkv,
                                                 bf16* __restrict__ WT,
                                                 bf16* __restrict__ WoT) {
  const int bid = blockIdx.x;
  if (bid < 12288) {
    const int by = bid >> 12, bx = bid & 4095;
    const float* in = by == 0 ? q : (by == 1 ? k : v);
    bf16* out = qkv + (size_t)by * 4194304;
    const size_t i = ((size_t)bx * 256 + threadIdx.x) * 4;
    const float4 vv = *(const float4*)(in + i);
    bf16x4 o;
    o[0] = (bf16)vv.x; o[1] = (bf16)vv.y; o[2] = (bf16)vv.z; o[3] = (bf16)vv.w;
    *(bf16x4*)(out + i) = o;
  } else if (bid < 24576) {
    const int b2 = bid - 12288;
    const int by = b2 >> 12;
    const float* W = by == 0 ? Wq : (by == 1 ? Wk : Wv);
    bf16* out = WT + (size_t)by * 1048576;
    const int idx = (b2 & 4095) * 256 + threadIdx.x;  // 1M
    const int n = idx >> 10, d = idx & 1023;
    out[idx] = (bf16)W[((n >> 6) << 16) + (d << 6) + (n & 63)];
  } else {
    const int idx = (bid - 24576) * 256 + threadIdx.x;  // 1M
    const int n = idx >> 10, kk = idx & 1023;
    WoT[idx] = (bf16)Wo[(kk << 10) + n];
  }
}

// ---------------- fused QKV GEMM: M=4096, K=1024, N=3072 ----------------
// 256x256 tile, BK=64, 8 waves (2M x 4N), 192 blocks (1/CU), LDS 128 KiB
// (2 buf x (A 32K + B 32K)). Counted-vmcnt pipeline: per K-tile
//   vmcnt(8); barrier            -- tile kt landed (kt+1's 8 loads in flight)
//   ds_read kk0 frags; 32 MFMA   -- ~300 cyc compute
//   ds_read kk1 frags; lgkmcnt(0); barrier   -- all waves done reading buf
//   stage kt+2 into the just-read buffer     -- >=1.5 phases before use
//   32 MFMA (kk1)
// LDS XOR-swizzle via pre-swizzled global source (c = ((t&7)-(t>>3))&7) and
// swizzled read (p = (quad + kk*4 + lane15)&7): 2 lanes/bank on ds_read_b128.
// K accumulation order identical to previous versions (ascending k32 slices).
__global__ __launch_bounds__(512, 2) void k_gemm_qkv(const bf16* __restrict__ Abase,
                                                     const bf16* __restrict__ Bt,
                                                     const float* __restrict__ bq,
                                                     const float* __restrict__ bk,
                                                     const float* __restrict__ bv,
                                                     bf16* __restrict__ Qh,
                                                     bf16* __restrict__ Kh,
                                                     bf16* __restrict__ Vt) {
  __shared__ __align__(16) bf16 lds[65536];  // 128 KiB: A [2][16384], B at +32768
  const int t = threadIdx.x;
  const int w = t >> 6;
  const int lane = t & 63;
  const int lane15 = lane & 15;
  const int quad = lane >> 4;
  const int wm = w >> 2;      // 0..1
  const int wn = w & 3;       // 0..3

  // XCD-aware bijective swizzle (192 blocks, 192 % 8 == 0)
  const int bid = blockIdx.x;
  const int swz = (bid & 7) * 24 + (bid >> 3);
  const int mb = swz & 15;    // 0..15
  const int nbf = swz >> 4;   // 0..11
  const int sel = nbf >> 2;   // 0=Q,1=K,2=V
  const int nbl = (nbf & 3) << 8;

  const bf16* A = Abase + (size_t)sel * 4194304;

  // stage source (per thread): row-in-64 = t>>3, logical chunk pre-swizzled
  const int sr = t >> 3;
  const int sc = ((t & 7) - sr) & 7;
  const bf16* AgS = A + (size_t)(mb * 256 + sr) * 1024 + sc * 8;
  const bf16* BgS = Bt + (size_t)(nbf * 256 + sr) * 1024 + sc * 8;

#define QKV_STAGE(kt, d)                                   \
  do {                                                     \
    const int _k = (kt) * 64;                              \
    bf16* _la = lds + (d)*16384 + t * 8;                   \
    bf16* _lb = lds + 32768 + (d)*16384 + t * 8;           \
    gl2lds16(AgS + _k, _la);                               \
    gl2lds16(AgS + 65536 + _k, _la + 4096);                \
    gl2lds16(AgS + 131072 + _k, _la + 8192);               \
    gl2lds16(AgS + 196608 + _k, _la + 12288);              \
    gl2lds16(BgS + _k, _lb);                               \
    gl2lds16(BgS + 65536 + _k, _lb + 4096);                \
    gl2lds16(BgS + 131072 + _k, _lb + 8192);               \
    gl2lds16(BgS + 196608 + _k, _lb + 12288);              \
  } while (0)

  f32x4 acc[8][4] = {};

  // read-side bases (element offsets); chunk term added per kk
  const int arow = (wm * 128 + lane15) * 64;
  const int brow = (wn * 64 + lane15) * 64 + 32768;

  // prologue: tiles 0,1 -> buffers 0,1 (16 loads/wave in flight)
  QKV_STAGE(0, 0);
  QKV_STAGE(1, 1);

#pragma unroll 2
  for (int kt = 0; kt < 16; ++kt) {
    const int d = kt & 1;
    if (kt == 15)
      asm volatile("s_waitcnt vmcnt(0)" ::: "memory");
    else
      asm volatile("s_waitcnt vmcnt(8)" ::: "memory");  // kt landed, kt+1 in flight
    __builtin_amdgcn_s_barrier();

    const int base = d * 16384;
    // ---- kk = 0 ----
    {
      const int p = ((quad + lane15) & 7) * 8;
      bf16x8 af[8], bfr[4];
#pragma unroll
      for (int i = 0; i < 8; ++i)
        af[i] = *(const bf16x8*)(lds + base + arow + i * 1024 + p);
#pragma unroll
      for (int j = 0; j < 4; ++j)
        bfr[j] = *(const bf16x8*)(lds + base + brow + j * 1024 + p);
      __builtin_amdgcn_s_setprio(1);
#pragma unroll
      for (int i = 0; i < 8; ++i)
#pragma unroll
        for (int j = 0; j < 4; ++j)
          acc[i][j] = __builtin_amdgcn_mfma_f32_16x16x32_bf16(af[i], bfr[j], acc[i][j], 0, 0, 0);
      __builtin_amdgcn_s_setprio(0);
    }
    // ---- kk = 1 reads, then free the buffer and stage over it ----
    {
      const int p = ((quad + 4 + lane15) & 7) * 8;
      bf16x8 ag[8], bg[4];
#pragma unroll
      for (int i = 0; i < 8; ++i)
        ag[i] = *(const bf16x8*)(lds + base + arow + i * 1024 + p);
#pragma unroll
      for (int j = 0; j < 4; ++j)
        bg[j] = *(const bf16x8*)(lds + base + brow + j * 1024 + p);
      asm volatile("s_waitcnt lgkmcnt(0)" ::: "memory");  // all reads of buf d done
      __builtin_amdgcn_s_barrier();
      if (kt < 14) QKV_STAGE(kt + 2, d);  // lands >=1.5 compute phases before use
      __builtin_amdgcn_s_setprio(1);
#pragma unroll
      for (int i = 0; i < 8; ++i)
#pragma unroll
        for (int j = 0; j < 4; ++j)
          acc[i][j] = __builtin_amdgcn_mfma_f32_16x16x32_bf16(ag[i], bg[j], acc[i][j], 0, 0, 0);
      __builtin_amdgcn_s_setprio(0);
    }
  }
#undef QKV_STAGE

  // ---- epilogue (same per-output math as previous versions) ----
  const float scale = sel == 0 ? 0.18033688011112042f : 1.0f;
  const float* bias = sel == 0 ? bq : (sel == 1 ? bk : bv);
  const int mbase = mb * 256 + wm * 128;
  if (sel < 2) {
    bf16* outp = sel == 0 ? Qh : Kh;
#pragma unroll
    for (int j = 0; j < 4; ++j) {
      const int n = nbl + wn * 64 + j * 16 + lane15;  // 0..1023
      const float bvl = bias[n];
      const int h = n >> 6, e = n & 63;
#pragma unroll
      for (int i = 0; i < 8; ++i) {
#pragma unroll
        for (int r = 0; r < 4; ++r) {
          const int m = mbase + i * 16 + quad * 4 + r;
          const float vv = (acc[i][j][r] + bvl) * scale;
          const int b = m >> 11, s = m & 2047;
          outp[(size_t)(b * 16 + h) * 131072 + s * 64 + e] = (bf16)vv;
        }
      }
    }
  } else {
    // V transposed [b,h,e,s]: r -> s contiguous, pack bf16x4 (8B) stores
#pragma unroll
    for (int j = 0; j < 4; ++j) {
      const int n = nbl + wn * 64 + j * 16 + lane15;
      const float bvl = bias[n];
      const int h = n >> 6, e = n & 63;
#pragma unroll
      for (int i = 0; i < 8; ++i) {
        const int m = mbase + i * 16 + quad * 4;
        const int b = m >> 11, s = m & 2047;
        bf16x4 o;
#pragma unroll
        for (int r = 0; r < 4; ++r) o[r] = (bf16)(acc[i][j][r] + bvl);
        *(bf16x4*)(Vt + (size_t)(b * 16 + h) * 131072 + e * 2048 + s) = o;
      }
    }
  }
}

// ---------------- flash attention ----------------
// Qh/Kh: [bh][2048][64] (Q pre-scaled, log2-domain); Vt: [bh][64][2048].
__global__ __launch_bounds__(512, 4) void k_attn(const bf16* __restrict__ Qh,
                                                 const bf16* __restrict__ Kh,
                                                 const bf16* __restrict__ Vt,
                                                 bf16* __restrict__ attn) {
  __shared__ __align__(16) bf16 lds[32768];  // 64 KiB: per half 16K elems (K dbuf 0/4096, V 8192/12288)
  const int t = threadIdx.x;
  const int w = t >> 6;        // 0..7
  const int lane = t & 63;
  const int lane31 = lane & 31;
  const int hi = lane >> 5;
  const int bh = blockIdx.y;
  const bf16* Qp = Qh + (size_t)bh * 131072;
  const bf16* Kp = Kh + (size_t)bh * 131072;
  const bf16* Vp = Vt + (size_t)bh * 131072;
  const int h = w >> 2;        // key-half
  const int q0 = blockIdx.x * 128 + (w & 3) * 32;

  // Q B-frags (n=q=lane31, k = kc*16 + hi*8 + j), loaded once
  bf16x8 aq[4];
#pragma unroll
  for (int kc = 0; kc < 4; ++kc)
    aq[kc] = *(const bf16x8*)(Qp + (size_t)(q0 + lane31) * 64 + kc * 16 + hi * 8);

  // swizzled LDS frag addresses (elements): row=lane31, chunk c = cc*2+hi
  int raddr[4];
#pragma unroll
  for (int cc = 0; cc < 4; ++cc)
    raddr[cc] = lane31 * 64 + (((cc * 2 + hi + lane31) & 7) << 3);

  // staging (per wave: 2 K-chunks + 2 V-chunks of 64 lanes x 16B, both halves)
  const bf16* kg[2];
  const bf16* vg[2];
  int kdst[2], vdst[2];
#pragma unroll
  for (int i = 0; i < 2; ++i) {
    const int cid = w * 2 + i;                   // 0..15
    const int half = cid >> 3;
    const int sl = ((cid & 7) << 6) + lane;      // 0..511 within half
    const int row = sl >> 3;
    const int c = ((sl & 7) - row) & 7;
    kg[i] = Kp + ((size_t)(half << 10) + row) * 64 + c * 8;
    vg[i] = Vp + (size_t)row * 2048 + (half << 10) + c * 8;
    kdst[i] = (half << 14) + ((cid & 7) << 9);
    vdst[i] = kdst[i] + 8192;
  }

  f32x16 O[2] = {};
  float l_ = 0.f;

  // prologue: stage tile 0 into buffer 0
#pragma unroll
  for (int i = 0; i < 2; ++i) {
    gl2lds16(kg[i], lds + kdst[i]);
    gl2lds16(vg[i], lds + vdst[i]);
  }

#pragma unroll 2
  for (int it = 0; it < 16; ++it) {
    const int bufo = (it & 1) << 12;
    __syncthreads();  // buffer[it&1] ready
    if (it + 1 < 16) {
      const int po = bufo ^ 4096;
#pragma unroll
      for (int i = 0; i < 2; ++i) {
        gl2lds16(kg[i] + (size_t)(it + 1) * 4096, lds + kdst[i] + po);
        gl2lds16(vg[i] + (it + 1) * 64, lds + vdst[i] + po);
      }
    }

    // ---- S^T = K * Q^T (rows=keys, cols=q) ----
    const bf16* Kl = lds + (h << 14) + bufo;
    f32x16 sa = {}, sb = {};
#pragma unroll
    for (int kc = 0; kc < 4; ++kc) {
      bf16x8 a0 = *(const bf16x8*)(Kl + raddr[kc]);
      bf16x8 a1 = *(const bf16x8*)(Kl + 2048 + raddr[kc]);
      sa = __builtin_amdgcn_mfma_f32_32x32x16_bf16(a0, aq[kc], sa, 0, 0, 0);
      sb = __builtin_amdgcn_mfma_f32_32x32x16_bf16(a1, aq[kc], sb, 0, 0, 0);
    }

    // ---- no-max exp2 softmax (scores bounded; P and l unnormalized) ----
    float rs = 0.f;
#pragma unroll
    for (int r = 0; r < 16; ++r) {
      sa[r] = __builtin_amdgcn_exp2f(sa[r]);
      sb[r] = __builtin_amdgcn_exp2f(sb[r]);
      rs += sa[r] + sb[r];
    }
    rs += __shfl_xor(rs, 32);
    l_ += rs;

    // ---- pack P pairs (C-reg pairs = consecutive keys) ----
    unsigned P2[2][8];
#pragma unroll
    for (int kq = 0; kq < 8; ++kq) {
      P2[0][kq] = pkbf(sa[2 * kq], sa[2 * kq + 1]);
      P2[1][kq] = pkbf(sb[2 * kq], sb[2 * kq + 1]);
    }

    // ---- transform C-layout -> B-frag (lane-half exchange) + PV ----
    const bf16* Vl = lds + (h << 14) + 8192 + bufo;
#pragma unroll
    for (int kk = 0; kk < 4; ++kk) {
      const int kmt = kk >> 1, kc = kk & 1;
      const unsigned mineA = hi ? P2[kmt][4 * kc + 2] : P2[kmt][4 * kc];
      const unsigned mineB = hi ? P2[kmt][4 * kc + 3] : P2[kmt][4 * kc + 1];
      const unsigned sendA = hi ? P2[kmt][4 * kc] : P2[kmt][4 * kc + 2];
      const unsigned sendB = hi ? P2[kmt][4 * kc + 1] : P2[kmt][4 * kc + 3];
      const unsigned ZA = (unsigned)__shfl_xor((int)sendA, 32);
      const unsigned ZB = (unsigned)__shfl_xor((int)sendB, 32);
      u32x4 bpi;
      bpi[0] = hi ? ZA : mineA;
      bpi[1] = hi ? ZB : mineB;
      bpi[2] = hi ? mineA : ZA;
      bpi[3] = hi ? mineB : ZB;
      const bf16x8 bp = __builtin_bit_cast(bf16x8, bpi);
#pragma unroll
      for (int emt = 0; emt < 2; ++emt) {
        bf16x8 av = *(const bf16x8*)(Vl + emt * 2048 + raddr[kk]);
        O[emt] = __builtin_amdgcn_mfma_f32_32x32x16_bf16(av, bp, O[emt], 0, 0, 0);
      }
    }
  }

  // ---- in-block merge of the two key-halves ----
  float* fl = (float*)lds;
  __syncthreads();
  if (w >= 4) {
#pragma unroll
    for (int emt = 0; emt < 2; ++emt)
#pragma unroll
      for (int r = 0; r < 16; ++r)
        fl[(w - 4) * 2048 + (emt * 16 + r) * 64 + lane] = O[emt][r];
    if (lane < 32) fl[8192 + (w - 4) * 32 + lane] = l_;
  }
  __syncthreads();
  if (w < 4) {
#pragma unroll
    for (int emt = 0; emt < 2; ++emt)
#pragma unroll
      for (int r = 0; r < 16; ++r)
        O[emt][r] += fl[w * 2048 + (emt * 16 + r) * 64 + lane];
    const float lsum = l_ + fl[8192 + w * 32 + lane31];
    const float inv = 1.0f / lsum;

    // epilogue: O^T[e][q] -> attn[b][q][h*64+e]
    const int b = bh >> 4, hh = bh & 15;
    const int q = q0 + lane31;
    bf16* orow = attn + (size_t)(b * 2048 + q) * 1024 + hh * 64;
#pragma unroll
    for (int emt = 0; emt < 2; ++emt) {
#pragma unroll
      for (int kp = 0; kp < 8; ++kp) {
        const int r = 2 * kp;
        const int e0 = emt * 32 + (r & 3) + 8 * (kp >> 1) + 4 * hi;
        bf16x2 pr;
        pr[0] = (bf16)(O[emt][r] * inv);
        pr[1] = (bf16)(O[emt][r + 1] * inv);
        *(bf16x2*)(orow + e0) = pr;
      }
    }
  }
}

// ---------------- final GEMM: 64x64 tile, M=4096 K=1024 N=1024, fp32 out ----------------
__global__ __launch_bounds__(256) void k_gemm2(const bf16* __restrict__ A,
                                               const bf16* __restrict__ Bt,
                                               const float* __restrict__ bias,
                                               float* __restrict__ outp) {
  __shared__ __align__(16) bf16 Alds[2048];  // 64 rows x 32 k
  __shared__ __align__(16) bf16 Blds[2048];
  const int t = threadIdx.x;
  const int w = t >> 6;
  const int lane = t & 63;
  const int lane15 = lane & 15;
  const int quad = lane >> 4;
  const int wm = w >> 1, wn = w & 1;
  const int mb = blockIdx.x, nb = blockIdx.y;  // 64 x 16

  const bf16* Ag = A + (size_t)(mb * 64 + (t & 63)) * 1024 + (t >> 6) * 8;
  const bf16* Bg = Bt + (size_t)(nb * 64 + (t & 63)) * 1024 + (t >> 6) * 8;
  bf16* Al = Alds + w * 512;  // [kchunk=w][row 0..63][8]
  bf16* Bl = Blds + w * 512;

  f32x4 acc[2][2] = {};

  for (int k0 = 0; k0 < 1024; k0 += 32) {
    __syncthreads();
    gl2lds16(Ag + k0, Al);
    gl2lds16(Bg + k0, Bl);
    __syncthreads();
    bf16x8 af[2], bfr[2];
#pragma unroll
    for (int i = 0; i < 2; ++i)
      af[i] = *(const bf16x8*)(Alds + (quad * 64 + wm * 32 + i * 16 + lane15) * 8);
#pragma unroll
    for (int j = 0; j < 2; ++j)
      bfr[j] = *(const bf16x8*)(Blds + (quad * 64 + wn * 32 + j * 16 + lane15) * 8);
#pragma unroll
    for (int i = 0; i < 2; ++i)
#pragma unroll
      for (int j = 0; j < 2; ++j)
        acc[i][j] = __builtin_amdgcn_mfma_f32_16x16x32_bf16(af[i], bfr[j], acc[i][j], 0, 0, 0);
  }

  const int mbase = mb * 64 + wm * 32;
  const int nbase = nb * 64 + wn * 32;
#pragma unroll
  for (int j = 0; j < 2; ++j) {
    const int n = nbase + j * 16 + lane15;
    const float bv = bias[n];
#pragma unroll
    for (int i = 0; i < 2; ++i) {
#pragma unroll
      for (int r = 0; r < 4; ++r) {
        const int m = mbase + i * 16 + quad * 4 + r;
        outp[(size_t)m * 1024 + n] = acc[i][j][r] + bv;
      }
    }
  }
}

// ---------------- launch ----------------
extern "C" void kernel_launch(void* const* d_in, const int* in_sizes, int n_in,
                              void* d_out, int out_size, void* d_ws, size_t ws_size,
                              hipStream_t stream) {
  (void)in_sizes; (void)n_in; (void)out_size; (void)ws_size;
  const float* q = (const float*)d_in[0];
  const float* k = (const float*)d_in[1];
  const float* v = (const float*)d_in[2];
  const float* Wq = (const float*)d_in[3];
  const float* bq = (const float*)d_in[4];
  const float* Wk = (const float*)d_in[5];
  const float* bk = (const float*)d_in[6];
  const float* Wv = (const float*)d_in[7];
  const float* bv = (const float*)d_in[8];
  const float* Wo = (const float*)d_in[9];
  const float* bo = (const float*)d_in[10];

  bf16* ws = (bf16*)d_ws;
  bf16* qkv = ws;                   // qb/kb/vb: 3 x 4M elems
  bf16* WqkvT = qkv + 12582912;     // 3 x 1M
  bf16* WoT = WqkvT + 3145728;      // 1M
  bf16* Qh = WoT + 1048576;         // 4M
  bf16* Kh = Qh + 4194304;          // 4M
  bf16* Vt = Kh + 4194304;          // 4M
  bf16* attnb = Vt + 4194304;       // 4M  (total 32M elems = 64 MiB)

  k_cvt_all<<<28672, 256, 0, stream>>>(q, k, v, Wq, Wk, Wv, Wo, qkv, WqkvT, WoT);
  k_gemm_qkv<<<192, 512, 0, stream>>>(qkv, WqkvT, bq, bk, bv, Qh, Kh, Vt);
  k_attn<<<dim3(16, 32), 512, 0, stream>>>(Qh, Kh, Vt, attnb);
  k_gemm2<<<dim3(64, 16), 256, 0, stream>>>(attnb, WoT, bo, (float*)d_out);
}

// Round 6
// 215.410 us; speedup vs baseline: 1.3117x; 1.2149x over previous
//
#include <hip/hip_runtime.h>
#include <cstdint>
#include <math.h>

// MHA: B=2, S=2048, D_MODEL=1024, H=16, D_HEAD=64.
// merged cvt (LDS-transposed W, coalesced both sides) -> fused QKV GEMM
// (128x128 tile, BK=64, 8 waves, counted-vmcnt dbuf, 768 blocks = 2/CU) ->
// flash attention (32x32x16 MFMA, S^T layout, no-max exp2 softmax) -> final
// GEMM (128x64 tile, BK=64, counted-vmcnt dbuf, 512 blocks).

typedef __bf16 bf16;
typedef __bf16 bf16x2 __attribute__((ext_vector_type(2)));
typedef __bf16 bf16x4 __attribute__((ext_vector_type(4)));
typedef __bf16 bf16x8 __attribute__((ext_vector_type(8)));
typedef float f32x4 __attribute__((ext_vector_type(4)));
typedef float f32x16 __attribute__((ext_vector_type(16)));
typedef unsigned u32x4 __attribute__((ext_vector_type(4)));

__device__ __forceinline__ void gl2lds16(const void* g, void* l) {
  __builtin_amdgcn_global_load_lds(
      (const __attribute__((address_space(1))) unsigned int*)g,
      (__attribute__((address_space(3))) unsigned int*)l,
      16, 0, 0);
}

__device__ __forceinline__ unsigned pkbf(float a, float b) {
  bf16x2 t;
  t[0] = (bf16)a;
  t[1] = (bf16)b;
  return __builtin_bit_cast(unsigned, t);
}

// ---------------- merged conversions (one dispatch, 13312 blocks) ----------------
// [0,12288): q/k/v fp32->bf16, coalesced float4 -> bf16x4
// [12288,13056): Wq/Wk/Wv [16][1024][64] -> WT[n=h*64+e][d] via LDS transpose
// [13056,13312): Wo [1024][1024] -> WoT[n][k] via LDS transpose
__global__ __launch_bounds__(256) void k_cvt_all(const float* __restrict__ q,
                                                 const float* __restrict__ k,
                                                 const float* __restrict__ v,
                                                 const float* __restrict__ Wq,
                                                 const float* __restrict__ Wk,
                                                 const float* __restrict__ Wv,
                                                 const float* __restrict__ Wo,
                                                 bf16* __restrict__ qkv,
                                                 bf16* __restrict__ WT,
                                                 bf16* __restrict__ WoT) {
  __shared__ float tl[64][65];
  const int bid = blockIdx.x;
  const int t = threadIdx.x;
  if (bid < 12288) {
    const int by = bid >> 12, bx = bid & 4095;
    const float* in = by == 0 ? q : (by == 1 ? k : v);
    bf16* out = qkv + (size_t)by * 4194304;
    const size_t i = ((size_t)bx * 256 + t) * 4;
    const float4 vv = *(const float4*)(in + i);
    bf16x4 o;
    o[0] = (bf16)vv.x; o[1] = (bf16)vv.y; o[2] = (bf16)vv.z; o[3] = (bf16)vv.w;
    *(bf16x4*)(out + i) = o;
  } else if (bid < 13056) {
    // W[h][d][e] -> WT[h*64+e][d], 64d x 64e tile per block
    const int wb = bid - 12288;
    const int sel = wb >> 8;
    const int rem = wb & 255;
    const int h = rem >> 4;
    const int d0 = (rem & 15) << 6;
    const float* W = sel == 0 ? Wq : (sel == 1 ? Wk : Wv);
    const int r = t >> 2;
    const float* srcp = W + (size_t)h * 65536 + (size_t)(d0 + r) * 64 + (t & 3) * 4;
#pragma unroll
    for (int j = 0; j < 4; ++j) {
      const float4 vv = *(const float4*)(srcp + j * 16);
      const int c = (t & 3) * 4 + j * 16;
      tl[r][c] = vv.x; tl[r][c + 1] = vv.y; tl[r][c + 2] = vv.z; tl[r][c + 3] = vv.w;
    }
    __syncthreads();
    bf16* dst = WT + (size_t)sel * 1048576;
#pragma unroll
    for (int pass = 0; pass < 2; ++pass) {
      const int e = (t >> 3) + pass * 32;
      const int dd = (t & 7) * 8;
      bf16x8 o;
#pragma unroll
      for (int j = 0; j < 8; ++j) o[j] = (bf16)tl[dd + j][e];
      *(bf16x8*)(dst + (size_t)(h * 64 + e) * 1024 + d0 + dd) = o;
    }
  } else {
    // Wo[k][n] -> WoT[n][k], 64k x 64n tile per block
    const int wb = bid - 13056;
    const int n0 = (wb >> 4) << 6;
    const int k0 = (wb & 15) << 6;
    const int r = t >> 2;
    const float* srcp = Wo + (size_t)(k0 + r) * 1024 + n0 + (t & 3) * 4;
#pragma unroll
    for (int j = 0; j < 4; ++j) {
      const float4 vv = *(const float4*)(srcp + j * 16);
      const int c = (t & 3) * 4 + j * 16;
      tl[r][c] = vv.x; tl[r][c + 1] = vv.y; tl[r][c + 2] = vv.z; tl[r][c + 3] = vv.w;
    }
    __syncthreads();
#pragma unroll
    for (int pass = 0; pass < 2; ++pass) {
      const int e = (t >> 3) + pass * 32;
      const int dd = (t & 7) * 8;
      bf16x8 o;
#pragma unroll
      for (int j = 0; j < 8; ++j) o[j] = (bf16)tl[dd + j][e];
      *(bf16x8*)(WoT + (size_t)(n0 + e) * 1024 + k0 + dd) = o;
    }
  }
}

// ---------------- fused QKV GEMM: M=4096, K=1024, N=3072 ----------------
// 128x128 tile, BK=64, 8 waves (2M x 4N, per-wave 64x32), 768 blocks = 2/CU
// (LDS 64 KiB dbuf), counted-vmcnt(4) pipeline:
//   vmcnt(4); barrier                -- tile kt landed (kt+1's 4 loads in flight)
//   kk0: ds_read 6 frags; 8 MFMA
//   kk1: ds_read; lgkmcnt(0); barrier; stage kt+2 over freed buffer; 8 MFMA
// LDS XOR-swizzle via pre-swizzled global source (c=((t&7)-sr)&7) + swizzled
// read (p=((quad[+4]+lane15)&7)*8). K accumulated in ascending 32-slices
// (bit-identical to all prior passing versions).
__global__ __launch_bounds__(512, 4) void k_gemm_qkv(const bf16* __restrict__ Abase,
                                                     const bf16* __restrict__ Bt,
                                                     const float* __restrict__ bq,
                                                     const float* __restrict__ bk,
                                                     const float* __restrict__ bv,
                                                     bf16* __restrict__ Qh,
                                                     bf16* __restrict__ Kh,
                                                     bf16* __restrict__ Vt) {
  __shared__ __align__(16) bf16 lds[32768];  // 64 KiB: A [2][8192] @0, B [2][8192] @16384
  const int t = threadIdx.x;
  const int lane = t & 63;
  const int lane15 = lane & 15;
  const int quad = lane >> 4;
  const int w = t >> 6;
  const int wm = w >> 2;      // 0..1
  const int wn = w & 3;       // 0..3

  // XCD-aware bijective swizzle (768 blocks, 96/XCD)
  const int bid = blockIdx.x;
  const int wgid = (bid & 7) * 96 + (bid >> 3);
  const int nb = wgid % 24;   // 0..23 (8 per sel)
  const int mb = wgid / 24;   // 0..31
  const int sel = nb >> 3;    // 0=Q,1=K,2=V
  const int nbl = (nb & 7) << 7;  // n base within 1024

  const bf16* A = Abase + (size_t)sel * 4194304;
  const int sr = t >> 3;              // 0..63
  const int sc = ((t & 7) - sr) & 7;  // pre-swizzled chunk
  const bf16* AgS = A + (size_t)(mb * 128 + sr) * 1024 + sc * 8;
  const bf16* BgS = Bt + (size_t)(nb * 128 + sr) * 1024 + sc * 8;

#define QKV_STAGE(kt, d)                           \
  do {                                             \
    const int _k = (kt) * 64;                      \
    bf16* _la = lds + (d) * 8192 + t * 8;          \
    bf16* _lb = lds + 16384 + (d) * 8192 + t * 8;  \
    gl2lds16(AgS + _k, _la);                       \
    gl2lds16(AgS + 65536 + _k, _la + 4096);        \
    gl2lds16(BgS + _k, _lb);                       \
    gl2lds16(BgS + 65536 + _k, _lb + 4096);        \
  } while (0)

  f32x4 acc[4][2] = {};
  const int arow = (wm * 64 + lane15) * 64;
  const int brow = 16384 + (wn * 32 + lane15) * 64;

  // prologue: tiles 0,1 -> buffers 0,1 (8 loads/thread in flight)
  QKV_STAGE(0, 0);
  QKV_STAGE(1, 1);

#pragma unroll 2
  for (int kt = 0; kt < 16; ++kt) {
    const int d = kt & 1;
    if (kt == 15)
      asm volatile("s_waitcnt vmcnt(0)" ::: "memory");
    else
      asm volatile("s_waitcnt vmcnt(4)" ::: "memory");  // kt landed, kt+1 in flight
    __builtin_amdgcn_s_barrier();
    const int base = d * 8192;
    // ---- kk = 0 (k 0..31 of tile) ----
    {
      const int p = ((quad + lane15) & 7) * 8;
      bf16x8 af[4], bfr[2];
#pragma unroll
      for (int i = 0; i < 4; ++i)
        af[i] = *(const bf16x8*)(lds + base + arow + i * 1024 + p);
#pragma unroll
      for (int j = 0; j < 2; ++j)
        bfr[j] = *(const bf16x8*)(lds + base + brow + j * 1024 + p);
      __builtin_amdgcn_s_setprio(1);
#pragma unroll
      for (int i = 0; i < 4; ++i)
#pragma unroll
        for (int j = 0; j < 2; ++j)
          acc[i][j] = __builtin_amdgcn_mfma_f32_16x16x32_bf16(af[i], bfr[j], acc[i][j], 0, 0, 0);
      __builtin_amdgcn_s_setprio(0);
    }
    // ---- kk = 1 (k 32..63): read, free buffer, stage over it ----
    {
      const int p = ((quad + 4 + lane15) & 7) * 8;
      bf16x8 ag[4], bg[2];
#pragma unroll
      for (int i = 0; i < 4; ++i)
        ag[i] = *(const bf16x8*)(lds + base + arow + i * 1024 + p);
#pragma unroll
      for (int j = 0; j < 2; ++j)
        bg[j] = *(const bf16x8*)(lds + base + brow + j * 1024 + p);
      asm volatile("s_waitcnt lgkmcnt(0)" ::: "memory");  // all reads of buf d done
      __builtin_amdgcn_s_barrier();
      if (kt < 14) QKV_STAGE(kt + 2, d);
      __builtin_amdgcn_s_setprio(1);
#pragma unroll
      for (int i = 0; i < 4; ++i)
#pragma unroll
        for (int j = 0; j < 2; ++j)
          acc[i][j] = __builtin_amdgcn_mfma_f32_16x16x32_bf16(ag[i], bg[j], acc[i][j], 0, 0, 0);
      __builtin_amdgcn_s_setprio(0);
    }
  }
#undef QKV_STAGE

  // ---- epilogue (per-output math identical to prior passing versions) ----
  const float scale = sel == 0 ? 0.18033688011112042f : 1.0f;
  const float* bias = sel == 0 ? bq : (sel == 1 ? bk : bv);
  const int mbase = mb * 128 + wm * 64;
  if (sel < 2) {
    bf16* outp = sel == 0 ? Qh : Kh;
#pragma unroll
    for (int j = 0; j < 2; ++j) {
      const int n = nbl + wn * 32 + j * 16 + lane15;  // 0..1023
      const float bvl = bias[n];
      const int h = n >> 6, e = n & 63;
#pragma unroll
      for (int i = 0; i < 4; ++i) {
#pragma unroll
        for (int r = 0; r < 4; ++r) {
          const int m = mbase + i * 16 + quad * 4 + r;
          const float vv = (acc[i][j][r] + bvl) * scale;
          const int b = m >> 11, s = m & 2047;
          outp[(size_t)(b * 16 + h) * 131072 + s * 64 + e] = (bf16)vv;
        }
      }
    }
  } else {
    // V transposed [b,h,e,s]: r -> s contiguous, pack bf16x4 (8B) stores
#pragma unroll
    for (int j = 0; j < 2; ++j) {
      const int n = nbl + wn * 32 + j * 16 + lane15;
      const float bvl = bias[n];
      const int h = n >> 6, e = n & 63;
#pragma unroll
      for (int i = 0; i < 4; ++i) {
        const int m = mbase + i * 16 + quad * 4;
        const int b = m >> 11, s = m & 2047;
        bf16x4 o;
#pragma unroll
        for (int r = 0; r < 4; ++r) o[r] = (bf16)(acc[i][j][r] + bvl);
        *(bf16x4*)(Vt + (size_t)(b * 16 + h) * 131072 + e * 2048 + s) = o;
      }
    }
  }
}

// ---------------- flash attention ----------------
// Qh/Kh: [bh][2048][64] (Q pre-scaled, log2-domain); Vt: [bh][64][2048].
__global__ __launch_bounds__(512, 4) void k_attn(const bf16* __restrict__ Qh,
                                                 const bf16* __restrict__ Kh,
                                                 const bf16* __restrict__ Vt,
                                                 bf16* __restrict__ attn) {
  __shared__ __align__(16) bf16 lds[32768];  // 64 KiB: per half 16K elems (K dbuf 0/4096, V 8192/12288)
  const int t = threadIdx.x;
  const int w = t >> 6;        // 0..7
  const int lane = t & 63;
  const int lane31 = lane & 31;
  const int hi = lane >> 5;
  const int bh = blockIdx.y;
  const bf16* Qp = Qh + (size_t)bh * 131072;
  const bf16* Kp = Kh + (size_t)bh * 131072;
  const bf16* Vp = Vt + (size_t)bh * 131072;
  const int h = w >> 2;        // key-half
  const int q0 = blockIdx.x * 128 + (w & 3) * 32;

  // Q B-frags (n=q=lane31, k = kc*16 + hi*8 + j), loaded once
  bf16x8 aq[4];
#pragma unroll
  for (int kc = 0; kc < 4; ++kc)
    aq[kc] = *(const bf16x8*)(Qp + (size_t)(q0 + lane31) * 64 + kc * 16 + hi * 8);

  // swizzled LDS frag addresses (elements): row=lane31, chunk c = cc*2+hi
  int raddr[4];
#pragma unroll
  for (int cc = 0; cc < 4; ++cc)
    raddr[cc] = lane31 * 64 + (((cc * 2 + hi + lane31) & 7) << 3);

  // staging (per wave: 2 K-chunks + 2 V-chunks of 64 lanes x 16B, both halves)
  const bf16* kg[2];
  const bf16* vg[2];
  int kdst[2], vdst[2];
#pragma unroll
  for (int i = 0; i < 2; ++i) {
    const int cid = w * 2 + i;                   // 0..15
    const int half = cid >> 3;
    const int sl = ((cid & 7) << 6) + lane;      // 0..511 within half
    const int row = sl >> 3;
    const int c = ((sl & 7) - row) & 7;
    kg[i] = Kp + ((size_t)(half << 10) + row) * 64 + c * 8;
    vg[i] = Vp + (size_t)row * 2048 + (half << 10) + c * 8;
    kdst[i] = (half << 14) + ((cid & 7) << 9);
    vdst[i] = kdst[i] + 8192;
  }

  f32x16 O[2] = {};
  float l_ = 0.f;

  // prologue: stage tile 0 into buffer 0
#pragma unroll
  for (int i = 0; i < 2; ++i) {
    gl2lds16(kg[i], lds + kdst[i]);
    gl2lds16(vg[i], lds + vdst[i]);
  }

#pragma unroll 2
  for (int it = 0; it < 16; ++it) {
    const int bufo = (it & 1) << 12;
    __syncthreads();  // buffer[it&1] ready
    if (it + 1 < 16) {
      const int po = bufo ^ 4096;
#pragma unroll
      for (int i = 0; i < 2; ++i) {
        gl2lds16(kg[i] + (size_t)(it + 1) * 4096, lds + kdst[i] + po);
        gl2lds16(vg[i] + (it + 1) * 64, lds + vdst[i] + po);
      }
    }

    // ---- S^T = K * Q^T (rows=keys, cols=q) ----
    const bf16* Kl = lds + (h << 14) + bufo;
    f32x16 sa = {}, sb = {};
#pragma unroll
    for (int kc = 0; kc < 4; ++kc) {
      bf16x8 a0 = *(const bf16x8*)(Kl + raddr[kc]);
      bf16x8 a1 = *(const bf16x8*)(Kl + 2048 + raddr[kc]);
      sa = __builtin_amdgcn_mfma_f32_32x32x16_bf16(a0, aq[kc], sa, 0, 0, 0);
      sb = __builtin_amdgcn_mfma_f32_32x32x16_bf16(a1, aq[kc], sb, 0, 0, 0);
    }

    // ---- no-max exp2 softmax (scores bounded; P and l unnormalized) ----
    float rs = 0.f;
#pragma unroll
    for (int r = 0; r < 16; ++r) {
      sa[r] = __builtin_amdgcn_exp2f(sa[r]);
      sb[r] = __builtin_amdgcn_exp2f(sb[r]);
      rs += sa[r] + sb[r];
    }
    rs += __shfl_xor(rs, 32);
    l_ += rs;

    // ---- pack P pairs (C-reg pairs = consecutive keys) ----
    unsigned P2[2][8];
#pragma unroll
    for (int kq = 0; kq < 8; ++kq) {
      P2[0][kq] = pkbf(sa[2 * kq], sa[2 * kq + 1]);
      P2[1][kq] = pkbf(sb[2 * kq], sb[2 * kq + 1]);
    }

    // ---- transform C-layout -> B-frag (lane-half exchange) + PV ----
    const bf16* Vl = lds + (h << 14) + 8192 + bufo;
#pragma unroll
    for (int kk = 0; kk < 4; ++kk) {
      const int kmt = kk >> 1, kc = kk & 1;
      const unsigned mineA = hi ? P2[kmt][4 * kc + 2] : P2[kmt][4 * kc];
      const unsigned mineB = hi ? P2[kmt][4 * kc + 3] : P2[kmt][4 * kc + 1];
      const unsigned sendA = hi ? P2[kmt][4 * kc] : P2[kmt][4 * kc + 2];
      const unsigned sendB = hi ? P2[kmt][4 * kc + 1] : P2[kmt][4 * kc + 3];
      const unsigned ZA = (unsigned)__shfl_xor((int)sendA, 32);
      const unsigned ZB = (unsigned)__shfl_xor((int)sendB, 32);
      u32x4 bpi;
      bpi[0] = hi ? ZA : mineA;
      bpi[1] = hi ? ZB : mineB;
      bpi[2] = hi ? mineA : ZA;
      bpi[3] = hi ? mineB : ZB;
      const bf16x8 bp = __builtin_bit_cast(bf16x8, bpi);
#pragma unroll
      for (int emt = 0; emt < 2; ++emt) {
        bf16x8 av = *(const bf16x8*)(Vl + emt * 2048 + raddr[kk]);
        O[emt] = __builtin_amdgcn_mfma_f32_32x32x16_bf16(av, bp, O[emt], 0, 0, 0);
      }
    }
  }

  // ---- in-block merge of the two key-halves ----
  float* fl = (float*)lds;
  __syncthreads();
  if (w >= 4) {
#pragma unroll
    for (int emt = 0; emt < 2; ++emt)
#pragma unroll
      for (int r = 0; r < 16; ++r)
        fl[(w - 4) * 2048 + (emt * 16 + r) * 64 + lane] = O[emt][r];
    if (lane < 32) fl[8192 + (w - 4) * 32 + lane] = l_;
  }
  __syncthreads();
  if (w < 4) {
#pragma unroll
    for (int emt = 0; emt < 2; ++emt)
#pragma unroll
      for (int r = 0; r < 16; ++r)
        O[emt][r] += fl[w * 2048 + (emt * 16 + r) * 64 + lane];
    const float lsum = l_ + fl[8192 + w * 32 + lane31];
    const float inv = 1.0f / lsum;

    // epilogue: O^T[e][q] -> attn[b][q][h*64+e]
    const int b = bh >> 4, hh = bh & 15;
    const int q = q0 + lane31;
    bf16* orow = attn + (size_t)(b * 2048 + q) * 1024 + hh * 64;
#pragma unroll
    for (int emt = 0; emt < 2; ++emt) {
#pragma unroll
      for (int kp = 0; kp < 8; ++kp) {
        const int r = 2 * kp;
        const int e0 = emt * 32 + (r & 3) + 8 * (kp >> 1) + 4 * hi;
        bf16x2 pr;
        pr[0] = (bf16)(O[emt][r] * inv);
        pr[1] = (bf16)(O[emt][r + 1] * inv);
        *(bf16x2*)(orow + e0) = pr;
      }
    }
  }
}

// ---------------- final GEMM: 128x64 tile, BK=64, M=4096 K=1024 N=1024 ----------------
// 512 blocks (2-3/CU), 4 waves (2M x 2N, per-wave 64x32), counted-vmcnt(6)
// dbuf pipeline, same swizzle scheme as k_gemm_qkv. fp32 out.
__global__ __launch_bounds__(256, 3) void k_gemm2(const bf16* __restrict__ A,
                                                  const bf16* __restrict__ Bt,
                                                  const float* __restrict__ bias,
                                                  float* __restrict__ outp) {
  __shared__ __align__(16) bf16 lds[24576];  // 48 KiB: A [2][8192] @0, B [2][4096] @16384
  const int t = threadIdx.x;
  const int lane = t & 63;
  const int lane15 = lane & 15;
  const int quad = lane >> 4;
  const int w = t >> 6;
  const int wm = w >> 1;   // 0..1
  const int wn = w & 1;    // 0..1

  // XCD-aware bijective swizzle (512 blocks, 64/XCD)
  const int bid = blockIdx.x;
  const int wgid = (bid & 7) * 64 + (bid >> 3);
  const int nb = wgid & 15;   // 0..15
  const int mb = wgid >> 4;   // 0..31

  const int sr = t >> 3;              // 0..31
  const int sc = ((t & 7) - sr) & 7;
  const bf16* AgS = A + (size_t)(mb * 128 + sr) * 1024 + sc * 8;
  const bf16* BgS = Bt + (size_t)(nb * 64 + sr) * 1024 + sc * 8;

#define G2_STAGE(kt, d)                            \
  do {                                             \
    const int _k = (kt) * 64;                      \
    bf16* _la = lds + (d) * 8192 + t * 8;          \
    bf16* _lb = lds + 16384 + (d) * 4096 + t * 8;  \
    gl2lds16(AgS + _k, _la);                       \
    gl2lds16(AgS + 32768 + _k, _la + 2048);        \
    gl2lds16(AgS + 65536 + _k, _la + 4096);        \
    gl2lds16(AgS + 98304 + _k, _la + 6144);        \
    gl2lds16(BgS + _k, _lb);                       \
    gl2lds16(BgS + 32768 + _k, _lb + 2048);        \
  } while (0)

  f32x4 acc[4][2] = {};
  const int arow = (wm * 64 + lane15) * 64;
  const int brow = 16384 + (wn * 32 + lane15) * 64;

  G2_STAGE(0, 0);
  G2_STAGE(1, 1);

#pragma unroll 2
  for (int kt = 0; kt < 16; ++kt) {
    const int d = kt & 1;
    if (kt == 15)
      asm volatile("s_waitcnt vmcnt(0)" ::: "memory");
    else
      asm volatile("s_waitcnt vmcnt(6)" ::: "memory");
    __builtin_amdgcn_s_barrier();
    const int baseA = d * 8192;
    const int baseB = d * 4096;
    // ---- kk = 0 ----
    {
      const int p = ((quad + lane15) & 7) * 8;
      bf16x8 af[4], bfr[2];
#pragma unroll
      for (int i = 0; i < 4; ++i)
        af[i] = *(const bf16x8*)(lds + baseA + arow + i * 1024 + p);
#pragma unroll
      for (int j = 0; j < 2; ++j)
        bfr[j] = *(const bf16x8*)(lds + baseB + brow + j * 1024 + p);
      __builtin_amdgcn_s_setprio(1);
#pragma unroll
      for (int i = 0; i < 4; ++i)
#pragma unroll
        for (int j = 0; j < 2; ++j)
          acc[i][j] = __builtin_amdgcn_mfma_f32_16x16x32_bf16(af[i], bfr[j], acc[i][j], 0, 0, 0);
      __builtin_amdgcn_s_setprio(0);
    }
    // ---- kk = 1 ----
    {
      const int p = ((quad + 4 + lane15) & 7) * 8;
      bf16x8 ag[4], bg[2];
#pragma unroll
      for (int i = 0; i < 4; ++i)
        ag[i] = *(const bf16x8*)(lds + baseA + arow + i * 1024 + p);
#pragma unroll
      for (int j = 0; j < 2; ++j)
        bg[j] = *(const bf16x8*)(lds + baseB + brow + j * 1024 + p);
      asm volatile("s_waitcnt lgkmcnt(0)" ::: "memory");
      __builtin_amdgcn_s_barrier();
      if (kt < 14) G2_STAGE(kt + 2, d);
      __builtin_amdgcn_s_setprio(1);
#pragma unroll
      for (int i = 0; i < 4; ++i)
#pragma unroll
        for (int j = 0; j < 2; ++j)
          acc[i][j] = __builtin_amdgcn_mfma_f32_16x16x32_bf16(ag[i], bg[j], acc[i][j], 0, 0, 0);
      __builtin_amdgcn_s_setprio(0);
    }
  }
#undef G2_STAGE

  const int mbase = mb * 128 + wm * 64;
  const int nbase = nb * 64 + wn * 32;
#pragma unroll
  for (int j = 0; j < 2; ++j) {
    const int n = nbase + j * 16 + lane15;
    const float bv = bias[n];
#pragma unroll
    for (int i = 0; i < 4; ++i) {
#pragma unroll
      for (int r = 0; r < 4; ++r) {
        const int m = mbase + i * 16 + quad * 4 + r;
        outp[(size_t)m * 1024 + n] = acc[i][j][r] + bv;
      }
    }
  }
}

// ---------------- launch ----------------
extern "C" void kernel_launch(void* const* d_in, const int* in_sizes, int n_in,
                              void* d_out, int out_size, void* d_ws, size_t ws_size,
                              hipStream_t stream) {
  (void)in_sizes; (void)n_in; (void)out_size; (void)ws_size;
  const float* q = (const float*)d_in[0];
  const float* k = (const float*)d_in[1];
  const float* v = (const float*)d_in[2];
  const float* Wq = (const float*)d_in[3];
  const float* bq = (const float*)d_in[4];
  const float* Wk = (const float*)d_in[5];
  const float* bk = (const float*)d_in[6];
  const float* Wv = (const float*)d_in[7];
  const float* bv = (const float*)d_in[8];
  const float* Wo = (const float*)d_in[9];
  const float* bo = (const float*)d_in[10];

  bf16* ws = (bf16*)d_ws;
  bf16* qkv = ws;                   // qb/kb/vb: 3 x 4M elems
  bf16* WqkvT = qkv + 12582912;     // 3 x 1M
  bf16* WoT = WqkvT + 3145728;      // 1M
  bf16* Qh = WoT + 1048576;         // 4M
  bf16* Kh = Qh + 4194304;          // 4M
  bf16* Vt = Kh + 4194304;          // 4M
  bf16* attnb = Vt + 4194304;       // 4M  (total 32M elems = 64 MiB)

  k_cvt_all<<<13312, 256, 0, stream>>>(q, k, v, Wq, Wk, Wv, Wo, qkv, WqkvT, WoT);
  k_gemm_qkv<<<768, 512, 0, stream>>>(qkv, WqkvT, bq, bk, bv, Qh, Kh, Vt);
  k_attn<<<dim3(16, 32), 512, 0, stream>>>(Qh, Kh, Vt, attnb);
  k_gemm2<<<512, 256, 0, stream>>>(attnb, WoT, bo, (float*)d_out);
}